// Round 1
// baseline (5105.129 us; speedup 1.0000x reference)
//
#include <hip/hip_runtime.h>
#include <hip/hip_bf16.h>

// ---------------------------------------------------------------------------
// DGLRGCN: 2-layer RGCN (R=5, H=256) + BN/ELU + MLP head, fp32.
// Strategy: aggregate-then-transform. S[r][dst] = sum of x[src] over edges of
// relation r, then h = sum_r S[r] @ W[r] + x[:nd] @ Wloop + b.
// ---------------------------------------------------------------------------

#define H 256
#define EPS 1e-5f

// ---------------- scatter: S[dst] += X[src] for edges with etype==r ---------
__global__ void scatter_rel_kernel(const float* __restrict__ X,
                                   const int* __restrict__ src,
                                   const int* __restrict__ dst,
                                   const int* __restrict__ et,
                                   int E, int r, float* __restrict__ S) {
    int id = blockIdx.x * blockDim.x + threadIdx.x;
    int e = id >> 6;
    int lane = id & 63;
    if (e >= E) return;
    if (et[e] != r) return;
    const float4* xr = reinterpret_cast<const float4*>(X + (size_t)src[e] * H);
    float4 v = xr[lane];
    float* p = S + (size_t)dst[e] * H + lane * 4;
    atomicAdd(p + 0, v.x);
    atomicAdd(p + 1, v.y);
    atomicAdd(p + 2, v.z);
    atomicAdd(p + 3, v.w);
}

// ---------------- scatter all relations: S[et][dst] += X[src] ---------------
__global__ void scatter_all_kernel(const float* __restrict__ X,
                                   const int* __restrict__ src,
                                   const int* __restrict__ dst,
                                   const int* __restrict__ et,
                                   int E, int nd, float* __restrict__ S) {
    int id = blockIdx.x * blockDim.x + threadIdx.x;
    int e = id >> 6;
    int lane = id & 63;
    if (e >= E) return;
    const float4* xr = reinterpret_cast<const float4*>(X + (size_t)src[e] * H);
    float4 v = xr[lane];
    float* p = S + ((size_t)et[e] * nd + dst[e]) * H + lane * 4;
    atomicAdd(p + 0, v.x);
    atomicAdd(p + 1, v.y);
    atomicAdd(p + 2, v.z);
    atomicAdd(p + 3, v.w);
}

// ---------------- tiled fp32 GEMM: C (+)= A[M,K] @ B[K,N] (+ bias) ----------
// block: 256 threads, 64x64 tile, 4x4 per-thread micro-tile, K-step 16.
__launch_bounds__(256)
__global__ void gemm_kernel(const float* __restrict__ A, int lda,
                            const float* __restrict__ B, int ldb,
                            const float* __restrict__ bias,
                            float* __restrict__ C, int ldc,
                            int M, int N, int K, int init) {
    __shared__ float As[16][65];
    __shared__ float Bs[16][65];
    int tid = threadIdx.x;
    int tx = tid & 15;        // col group
    int ty = tid >> 4;        // row group
    int row0 = blockIdx.y * 64;
    int col0 = blockIdx.x * 64;
    float acc[4][4] = {};

    for (int kk = 0; kk < K; kk += 16) {
        // load A tile (64 m x 16 k), coalesced along k
        {
            int k = tid & 15;
            int mBase = tid >> 4;
#pragma unroll
            for (int l = 0; l < 4; l++) {
                int m = mBase + l * 16;
                int gr = row0 + m;
                As[k][m] = (gr < M) ? A[(size_t)gr * lda + kk + k] : 0.f;
            }
        }
        // load B tile (16 k x 64 n), coalesced along n
        {
            int n = tid & 63;
            int kBase = tid >> 6;
#pragma unroll
            for (int l = 0; l < 4; l++) {
                int k = kBase + l * 4;
                int gc = col0 + n;
                Bs[k][n] = (gc < N) ? B[(size_t)(kk + k) * ldb + gc] : 0.f;
            }
        }
        __syncthreads();
#pragma unroll
        for (int k = 0; k < 16; k++) {
            float a[4], b[4];
#pragma unroll
            for (int i = 0; i < 4; i++) a[i] = As[k][ty * 4 + i];
#pragma unroll
            for (int j = 0; j < 4; j++) b[j] = Bs[k][tx * 4 + j];
#pragma unroll
            for (int i = 0; i < 4; i++)
#pragma unroll
                for (int j = 0; j < 4; j++) acc[i][j] += a[i] * b[j];
        }
        __syncthreads();
    }

#pragma unroll
    for (int i = 0; i < 4; i++) {
        int gr = row0 + ty * 4 + i;
        if (gr >= M) continue;
#pragma unroll
        for (int j = 0; j < 4; j++) {
            int gc = col0 + tx * 4 + j;
            if (gc >= N) continue;
            float v = acc[i][j];
            if (init) {
                if (bias) v += bias[gc];
                C[(size_t)gr * ldc + gc] = v;
            } else {
                C[(size_t)gr * ldc + gc] += v;
            }
        }
    }
}

// ---------------- BN column stats: sums[c]=sum, sums[256+c]=sumsq ----------
__global__ void bn_stats_kernel(const float* __restrict__ Hm, int M,
                                float* __restrict__ sums) {
    int col = threadIdx.x;  // 256 threads = 256 cols
    int rows_per = (M + gridDim.x - 1) / gridDim.x;
    int r0 = blockIdx.x * rows_per;
    int r1 = min(M, r0 + rows_per);
    float s = 0.f, s2 = 0.f;
    for (int i = r0; i < r1; i++) {
        float v = Hm[(size_t)i * H + col];
        s += v;
        s2 += v * v;
    }
    if (r1 > r0) {
        atomicAdd(&sums[col], s);
        atomicAdd(&sums[H + col], s2);
    }
}

// ---------------- BN normalize + activation (0=ELU, 1=ReLU), in place ------
__global__ void bn_apply_kernel(float* __restrict__ Hm, int M,
                                const float* __restrict__ sums,
                                const float* __restrict__ g,
                                const float* __restrict__ be, int relu) {
    int id = blockIdx.x * blockDim.x + threadIdx.x;
    if (id >= M * 64) return;
    int row = id >> 6;
    int l = id & 63;
    float4* p = reinterpret_cast<float4*>(Hm + (size_t)row * H) + l;
    float4 v4 = *p;
    float vv[4] = {v4.x, v4.y, v4.z, v4.w};
    float invM = 1.f / (float)M;
    int c = l * 4;
    float out[4];
#pragma unroll
    for (int j = 0; j < 4; j++) {
        float mu = sums[c + j] * invM;
        float var = sums[H + c + j] * invM - mu * mu;
        float t = g[c + j] * (vv[j] - mu) * rsqrtf(var + EPS) + be[c + j];
        out[j] = relu ? fmaxf(t, 0.f) : (t > 0.f ? t : expm1f(t));
    }
    *p = make_float4(out[0], out[1], out[2], out[3]);
}

// ---------------------------------------------------------------------------
static inline void launch_gemm(const float* A, int lda, const float* B, int ldb,
                               const float* bias, float* C, int ldc,
                               int M, int N, int K, int init, hipStream_t s) {
    dim3 grid((N + 63) / 64, (M + 63) / 64);
    gemm_kernel<<<grid, 256, 0, s>>>(A, lda, B, ldb, bias, C, ldc, M, N, K, init);
}

extern "C" void kernel_launch(void* const* d_in, const int* in_sizes, int n_in,
                              void* d_out, int out_size, void* d_ws, size_t ws_size,
                              hipStream_t stream) {
    const float* x   = (const float*)d_in[0];
    const int* src0  = (const int*)d_in[1];
    const int* dst0  = (const int*)d_in[2];
    const int* et0   = (const int*)d_in[3];
    const int* src1  = (const int*)d_in[4];
    const int* dst1  = (const int*)d_in[5];
    const int* et1   = (const int*)d_in[6];
    const float* W0  = (const float*)d_in[9];
    const float* Wl0 = (const float*)d_in[10];
    const float* b0  = (const float*)d_in[11];
    const float* g0  = (const float*)d_in[12];
    const float* be0 = (const float*)d_in[13];
    const float* W1  = (const float*)d_in[14];
    const float* Wl1 = (const float*)d_in[15];
    const float* b1  = (const float*)d_in[16];
    const float* g1  = (const float*)d_in[17];
    const float* be1 = (const float*)d_in[18];
    const float* Wm1 = (const float*)d_in[19];
    const float* bm1 = (const float*)d_in[20];
    const float* gm  = (const float*)d_in[21];
    const float* bem = (const float*)d_in[22];
    const float* Wm2 = (const float*)d_in[23];
    const float* bm2 = (const float*)d_in[24];

    const int E0 = in_sizes[1];
    const int E1 = in_sizes[4];
    const int NOUT = in_sizes[24];   // 153
    const int ND0 = 50000;
    const int ND1 = 10000;
    const int R = 5;

    float* ws = (float*)d_ws;
    float* S  = ws;                       // 12.8M floats (51.2 MB), reused
    float* h0 = ws + 12800000;            // 12.8M floats
    float* h1 = ws + 25600000;            // 2.56M floats
    float* mb = ws + 28160000;            // 2.56M floats
    float* st = ws + 30720000;            // 1536 floats (3 x 512 BN stats)

    hipMemsetAsync(st, 0, 1536 * sizeof(float), stream);

    // ---------------- layer 0 ----------------
    // self-loop init: h0 = x[:ND0] @ Wl0 + b0
    launch_gemm(x, H, Wl0, H, b0, h0, H, ND0, H, H, 1, stream);
    int sc_grid0 = (E0 * 64 + 255) / 256;
    for (int r = 0; r < R; r++) {
        hipMemsetAsync(S, 0, (size_t)ND0 * H * sizeof(float), stream);
        scatter_rel_kernel<<<sc_grid0, 256, 0, stream>>>(x, src0, dst0, et0, E0, r, S);
        launch_gemm(S, H, W0 + (size_t)r * H * H, H, nullptr, h0, H, ND0, H, H, 0, stream);
    }
    bn_stats_kernel<<<256, 256, 0, stream>>>(h0, ND0, st);
    bn_apply_kernel<<<(ND0 * 64 + 255) / 256, 256, 0, stream>>>(h0, ND0, st, g0, be0, 0);

    // ---------------- layer 1 ----------------
    launch_gemm(h0, H, Wl1, H, b1, h1, H, ND1, H, H, 1, stream);
    hipMemsetAsync(S, 0, (size_t)R * ND1 * H * sizeof(float), stream);
    int sc_grid1 = (E1 * 64 + 255) / 256;
    scatter_all_kernel<<<sc_grid1, 256, 0, stream>>>(h0, src1, dst1, et1, E1, ND1, S);
    for (int r = 0; r < R; r++) {
        launch_gemm(S + (size_t)r * ND1 * H, H, W1 + (size_t)r * H * H, H, nullptr,
                    h1, H, ND1, H, H, 0, stream);
    }
    bn_stats_kernel<<<256, 256, 0, stream>>>(h1, ND1, st + 512);
    bn_apply_kernel<<<(ND1 * 64 + 255) / 256, 256, 0, stream>>>(h1, ND1, st + 512, g1, be1, 0);

    // ---------------- MLP head ----------------
    launch_gemm(h1, H, Wm1, H, bm1, mb, H, ND1, H, H, 1, stream);
    bn_stats_kernel<<<256, 256, 0, stream>>>(mb, ND1, st + 1024);
    bn_apply_kernel<<<(ND1 * 64 + 255) / 256, 256, 0, stream>>>(mb, ND1, st + 1024, gm, bem, 1);
    launch_gemm(mb, H, Wm2, NOUT, bm2, (float*)d_out, NOUT, ND1, NOUT, H, 1, stream);
}

// Round 2
// 984.795 us; speedup vs baseline: 5.1840x; 5.1840x over previous
//
#include <hip/hip_runtime.h>
#include <hip/hip_bf16.h>

// ---------------------------------------------------------------------------
// DGLRGCN on MI355X. Aggregate-then-transform with CSR bucketing (no atomics)
// + fused bf16 MFMA GEMMs (K = 6*256: 5 relations + self-loop).
// ---------------------------------------------------------------------------

#define HD   256
#define EPS  1e-5f
#define NREL 5
#define ND0  50000
#define ND1  10000
#define BK   64
#define PAD  8      // LDS row pad (ushorts): row stride 72 -> 36 dwords

typedef unsigned short ushort_t;
using f32x4  = __attribute__((ext_vector_type(4))) float;
using short8 = __attribute__((ext_vector_type(8))) short;

__device__ __forceinline__ ushort_t f2b(float f) {
    union { float f; unsigned u; } x; x.f = f;
    unsigned r = x.u + 0x7FFF + ((x.u >> 16) & 1);   // RNE
    return (ushort_t)(r >> 16);
}
__device__ __forceinline__ float b2f(ushort_t h) {
    union { unsigned u; float f; } x; x.u = ((unsigned)h) << 16;
    return x.f;
}

// ---------------- weight convert: src[K][N] fp32 -> dst[Nout][K] bf16 -------
__global__ void wconv_kernel(const float* __restrict__ src, ushort_t* __restrict__ dst,
                             int K, int N, int Nout) {
    int id = blockIdx.x * 256 + threadIdx.x;
    if (id >= Nout * K) return;
    int n = id / K, k = id - n * K;
    float v = (n < N) ? src[(size_t)k * N + n] : 0.f;
    dst[id] = f2b(v);
}

// ---------------- CSR build ------------------------------------------------
__global__ void count_kernel(const int* __restrict__ dst, const int* __restrict__ et,
                             int E, int ND, int* __restrict__ cnt, int* __restrict__ pos) {
    int e = blockIdx.x * 256 + threadIdx.x;
    if (e >= E) return;
    pos[e] = atomicAdd(&cnt[et[e] * ND + dst[e]], 1);
}

// exclusive scan, 1024 elems/block; bsum (if non-null) gets block totals
__global__ void scan_block_kernel(const int* __restrict__ in, int* __restrict__ out,
                                  int* __restrict__ bsum, int nb) {
    __shared__ int ts[256];
    int tid = threadIdx.x;
    int base = blockIdx.x * 1024 + tid * 4;
    int v0 = (base + 0 < nb) ? in[base + 0] : 0;
    int v1 = (base + 1 < nb) ? in[base + 1] : 0;
    int v2 = (base + 2 < nb) ? in[base + 2] : 0;
    int v3 = (base + 3 < nb) ? in[base + 3] : 0;
    int tsum = v0 + v1 + v2 + v3;
    ts[tid] = tsum;
    __syncthreads();
    for (int d = 1; d < 256; d <<= 1) {
        int t = (tid >= d) ? ts[tid - d] : 0;
        __syncthreads();
        ts[tid] += t;
        __syncthreads();
    }
    int excl = ts[tid] - tsum;
    if (base + 0 < nb) out[base + 0] = excl;
    if (base + 1 < nb) out[base + 1] = excl + v0;
    if (base + 2 < nb) out[base + 2] = excl + v0 + v1;
    if (base + 3 < nb) out[base + 3] = excl + v0 + v1 + v2;
    if (tid == 255 && bsum) bsum[blockIdx.x] = ts[255];
}

__global__ void scan_add_kernel(int* __restrict__ out, const int* __restrict__ bsum, int nb) {
    int i = blockIdx.x * 256 + threadIdx.x;
    if (i < nb) out[i] += bsum[i >> 10];
}

__global__ void fill_kernel(const int* __restrict__ src, const int* __restrict__ dst,
                            const int* __restrict__ et, const int* __restrict__ pos,
                            const int* __restrict__ off, int E, int ND,
                            int* __restrict__ ssrc) {
    int e = blockIdx.x * 256 + threadIdx.x;
    if (e >= E) return;
    ssrc[off[et[e] * ND + dst[e]] + pos[e]] = src[e];
}

// ---------------- gather-sum (one wave per (r,dst) bucket), no atomics ------
__global__ void gather_f32_kernel(const float* __restrict__ feat, const int* __restrict__ ssrc,
                                  const int* __restrict__ cnt, const int* __restrict__ off,
                                  int ND, int c0, int rows, ushort_t* __restrict__ out) {
    int wave = (blockIdx.x * 256 + threadIdx.x) >> 6;
    int lane = threadIdx.x & 63;
    if (wave >= NREL * rows) return;
    int r = wave / rows, i = wave - r * rows;
    int b = r * ND + c0 + i;
    int deg = cnt[b], s = off[b];
    float a0 = 0, a1 = 0, a2 = 0, a3 = 0;
    for (int j = 0; j < deg; j++) {
        int row = ssrc[s + j];
        float4 v = ((const float4*)(feat + (size_t)row * HD))[lane];
        a0 += v.x; a1 += v.y; a2 += v.z; a3 += v.w;
    }
    ushort4 o; o.x = f2b(a0); o.y = f2b(a1); o.z = f2b(a2); o.w = f2b(a3);
    ((ushort4*)(out + (size_t)wave * HD))[lane] = o;
}

__global__ void gather_b16_kernel(const ushort_t* __restrict__ feat, const int* __restrict__ ssrc,
                                  const int* __restrict__ cnt, const int* __restrict__ off,
                                  int ND, int c0, int rows, ushort_t* __restrict__ out) {
    int wave = (blockIdx.x * 256 + threadIdx.x) >> 6;
    int lane = threadIdx.x & 63;
    if (wave >= NREL * rows) return;
    int r = wave / rows, i = wave - r * rows;
    int b = r * ND + c0 + i;
    int deg = cnt[b], s = off[b];
    float a0 = 0, a1 = 0, a2 = 0, a3 = 0;
    for (int j = 0; j < deg; j++) {
        int row = ssrc[s + j];
        ushort4 v = ((const ushort4*)(feat + (size_t)row * HD))[lane];
        a0 += b2f(v.x); a1 += b2f(v.y); a2 += b2f(v.z); a3 += b2f(v.w);
    }
    ushort4 o; o.x = f2b(a0); o.y = f2b(a1); o.z = f2b(a2); o.w = f2b(a3);
    ((ushort4*)(out + (size_t)wave * HD))[lane] = o;
}

// ---------------- fused MFMA GEMM: C = [A_0|..|A_{n-1}] @ [B_0;..] + bias ---
// Each segment s: A_s row-major [M][256] (bf16 or fp32), B_s bf16 [256n][256k]
// (n-major). Block = 256 thr (4 waves 2x2), tile 128x128, wave 64x64 via 4x4
// mfma_f32_16x16x32_bf16. A reads past M are unguarded (land in ws, finite,
// discarded by the store guard).
struct GemmArgs {
    const void*     A[6];
    const ushort_t* B[6];
    int             a_f32[6];
    int             nseg;
    const float*    bias;
    ushort_t*       Cb;      // bf16 out, stride 256 (or null)
    float*          Cf;      // fp32 out, stride N  (or null)
    int             M, N;
};

__launch_bounds__(256)
__global__ void gemm_mfma_kernel(GemmArgs g) {
    __shared__ __align__(16) ushort_t As[128][BK + PAD];
    __shared__ __align__(16) ushort_t Bs[128][BK + PAD];
    int tid = threadIdx.x;
    int wave = tid >> 6, lane = tid & 63;
    int wm = (wave >> 1) * 64, wn = (wave & 1) * 64;
    int bm = blockIdx.y * 128, bn = blockIdx.x * 128;
    f32x4 acc[4][4] = {};
    int K = g.nseg * HD;

    for (int kk = 0; kk < K; kk += BK) {
        int s = kk >> 8;
        int kl = kk & 255;
        // --- A tile: rows bm..bm+127, k kl..kl+63
        if (g.a_f32[s]) {
            const float* Ap = (const float*)g.A[s];
#pragma unroll
            for (int it = 0; it < 8; it++) {
                int idx = tid + it * 256;          // 0..2047
                int row = idx >> 4, c4 = idx & 15;
                float4 v = ((const float4*)(Ap + (size_t)(bm + row) * HD + kl))[c4];
                uint2 p;
                p.x = (unsigned)f2b(v.x) | ((unsigned)f2b(v.y) << 16);
                p.y = (unsigned)f2b(v.z) | ((unsigned)f2b(v.w) << 16);
                *(uint2*)&As[row][c4 * 4] = p;
            }
        } else {
            const ushort_t* Ap = (const ushort_t*)g.A[s];
#pragma unroll
            for (int it = 0; it < 4; it++) {
                int idx = tid + it * 256;          // 0..1023
                int row = idx >> 3, c8 = idx & 7;
                uint4 v = *(const uint4*)(Ap + (size_t)(bm + row) * HD + kl + c8 * 8);
                *(uint4*)&As[row][c8 * 8] = v;
            }
        }
        // --- B tile: n-rows bn..bn+127, k kl..kl+63 (B stored [n][k])
        {
            const ushort_t* Bp = g.B[s];
#pragma unroll
            for (int it = 0; it < 4; it++) {
                int idx = tid + it * 256;
                int row = idx >> 3, c8 = idx & 7;
                uint4 v = *(const uint4*)(Bp + (size_t)(bn + row) * HD + kl + c8 * 8);
                *(uint4*)&Bs[row][c8 * 8] = v;
            }
        }
        __syncthreads();
#pragma unroll
        for (int ks = 0; ks < BK; ks += 32) {
            int kq = ks + (lane >> 4) * 8;
            short8 a[4], b[4];
#pragma unroll
            for (int mi = 0; mi < 4; mi++)
                a[mi] = *(const short8*)&As[wm + mi * 16 + (lane & 15)][kq];
#pragma unroll
            for (int ni = 0; ni < 4; ni++)
                b[ni] = *(const short8*)&Bs[wn + ni * 16 + (lane & 15)][kq];
#pragma unroll
            for (int mi = 0; mi < 4; mi++)
#pragma unroll
                for (int ni = 0; ni < 4; ni++)
                    acc[mi][ni] = __builtin_amdgcn_mfma_f32_16x16x32_bf16(
                        a[mi], b[ni], acc[mi][ni], 0, 0, 0);
        }
        __syncthreads();
    }

    int rq = lane >> 4, ci = lane & 15;
#pragma unroll
    for (int mi = 0; mi < 4; mi++)
#pragma unroll
        for (int ni = 0; ni < 4; ni++)
#pragma unroll
            for (int reg = 0; reg < 4; reg++) {
                int row = bm + wm + mi * 16 + rq * 4 + reg;
                int col = bn + wn + ni * 16 + ci;
                if (row < g.M && col < g.N) {
                    float v = acc[mi][ni][reg];
                    if (g.bias) v += g.bias[col];
                    if (g.Cb) g.Cb[(size_t)row * HD + col] = f2b(v);
                    else      g.Cf[(size_t)row * g.N + col] = v;
                }
            }
}

// ---------------- BN ------------------------------------------------------
__global__ void bn_stats_kernel(const ushort_t* __restrict__ Hb, int M,
                                float* __restrict__ sums) {
    int col = threadIdx.x;
    float s = 0.f, s2 = 0.f;
    for (int i = blockIdx.x; i < M; i += gridDim.x) {
        float v = b2f(Hb[(size_t)i * HD + col]);
        s += v; s2 += v * v;
    }
    atomicAdd(&sums[col], s);
    atomicAdd(&sums[HD + col], s2);
}

__global__ void bn_apply_kernel(ushort_t* __restrict__ Hb, int M,
                                const float* __restrict__ sums,
                                const float* __restrict__ g,
                                const float* __restrict__ be, int relu) {
    int id = blockIdx.x * 256 + threadIdx.x;
    if (id >= M * 64) return;
    int row = id >> 6, l = id & 63;
    ushort4* p = (ushort4*)(Hb + (size_t)row * HD) + l;
    ushort4 v4 = *p;
    float vv[4] = {b2f(v4.x), b2f(v4.y), b2f(v4.z), b2f(v4.w)};
    float invM = 1.f / (float)M;
    int c = l * 4;
    ushort4 o;
    ushort_t* op = (ushort_t*)&o;
#pragma unroll
    for (int j = 0; j < 4; j++) {
        float mu = sums[c + j] * invM;
        float var = sums[HD + c + j] * invM - mu * mu;
        float t = g[c + j] * (vv[j] - mu) * rsqrtf(var + EPS) + be[c + j];
        t = relu ? fmaxf(t, 0.f) : (t > 0.f ? t : expm1f(t));
        op[j] = f2b(t);
    }
    *p = o;
}

// ---------------------------------------------------------------------------
extern "C" void kernel_launch(void* const* d_in, const int* in_sizes, int n_in,
                              void* d_out, int out_size, void* d_ws, size_t ws_size,
                              hipStream_t stream) {
    const float* x   = (const float*)d_in[0];
    const int* src0  = (const int*)d_in[1];
    const int* dst0  = (const int*)d_in[2];
    const int* et0   = (const int*)d_in[3];
    const int* src1  = (const int*)d_in[4];
    const int* dst1  = (const int*)d_in[5];
    const int* et1   = (const int*)d_in[6];
    const float* W0  = (const float*)d_in[9];
    const float* Wl0 = (const float*)d_in[10];
    const float* b0  = (const float*)d_in[11];
    const float* g0  = (const float*)d_in[12];
    const float* be0 = (const float*)d_in[13];
    const float* W1  = (const float*)d_in[14];
    const float* Wl1 = (const float*)d_in[15];
    const float* b1  = (const float*)d_in[16];
    const float* g1  = (const float*)d_in[17];
    const float* be1 = (const float*)d_in[18];
    const float* Wm1 = (const float*)d_in[19];
    const float* bm1 = (const float*)d_in[20];
    const float* gm  = (const float*)d_in[21];
    const float* bem = (const float*)d_in[22];
    const float* Wm2 = (const float*)d_in[23];
    const float* bm2 = (const float*)d_in[24];

    const int E0 = in_sizes[1];
    const int E1 = in_sizes[4];
    const int NOUT = in_sizes[24];   // 153

    // ---------------- ws layout (all 16B-aligned; total ~100 MB) ----------
    ushort_t* W0t  = (ushort_t*)d_ws;            // 5*65536
    ushort_t* Wl0t = W0t + 5 * 65536;
    ushort_t* W1t  = Wl0t + 65536;
    ushort_t* Wl1t = W1t + 5 * 65536;
    ushort_t* Wm1t = Wl1t + 65536;
    ushort_t* Wm2t = Wm1t + 65536;               // padded to 256 rows
    float* st  = (float*)(Wm2t + 65536);         // 1536
    int* cnt   = (int*)(st + 1536);              // 250000
    int* off   = cnt + 250000;                   // 250000
    int* bsum  = off + 250000;                   // 1024
    int* pos   = bsum + 1024;                    // 800000
    int* ssrc  = pos + 800000;                   // 800000
    ushort_t* h0b   = (ushort_t*)(ssrc + 800000);        // 50000*256
    ushort_t* arena = h0b + (size_t)ND0 * HD;            // 32M ushorts (64 MB)
    ushort_t* S0c = arena;                               // 5*25000*256
    ushort_t* S1  = arena;                               // 5*10000*256 (after gemm0)
    ushort_t* h1b = arena + (size_t)NREL * ND1 * HD;     // 10000*256
    ushort_t* mb  = h1b + (size_t)ND1 * HD;              // 10000*256

    // ---------------- weights -> bf16 transposed ---------------------------
    for (int r = 0; r < NREL; r++)
        wconv_kernel<<<256, 256, 0, stream>>>(W0 + (size_t)r * 65536, W0t + (size_t)r * 65536, 256, 256, 256);
    wconv_kernel<<<256, 256, 0, stream>>>(Wl0, Wl0t, 256, 256, 256);
    for (int r = 0; r < NREL; r++)
        wconv_kernel<<<256, 256, 0, stream>>>(W1 + (size_t)r * 65536, W1t + (size_t)r * 65536, 256, 256, 256);
    wconv_kernel<<<256, 256, 0, stream>>>(Wl1, Wl1t, 256, 256, 256);
    wconv_kernel<<<256, 256, 0, stream>>>(Wm1, Wm1t, 256, 256, 256);
    wconv_kernel<<<256, 256, 0, stream>>>(Wm2, Wm2t, 256, NOUT, 256);

    hipMemsetAsync(st, 0, 1536 * sizeof(float), stream);

    // ---------------- layer 0: CSR + 2 chunks of (gather, fused GEMM) ------
    hipMemsetAsync(cnt, 0, NREL * ND0 * sizeof(int), stream);
    count_kernel<<<(E0 + 255) / 256, 256, 0, stream>>>(dst0, et0, E0, ND0, cnt, pos);
    scan_block_kernel<<<(NREL * ND0 + 1023) / 1024, 256, 0, stream>>>(cnt, off, bsum, NREL * ND0);
    scan_block_kernel<<<1, 256, 0, stream>>>(bsum, bsum, nullptr, (NREL * ND0 + 1023) / 1024);
    scan_add_kernel<<<(NREL * ND0 + 255) / 256, 256, 0, stream>>>(off, bsum, NREL * ND0);
    fill_kernel<<<(E0 + 255) / 256, 256, 0, stream>>>(src0, dst0, et0, pos, off, E0, ND0, ssrc);

    for (int c = 0; c < 2; c++) {
        int c0 = c * 25000, rows = 25000;
        gather_f32_kernel<<<(NREL * rows * 64) / 256, 256, 0, stream>>>(
            x, ssrc, cnt, off, ND0, c0, rows, S0c);
        GemmArgs ga = {};
        for (int s = 0; s < NREL; s++) {
            ga.A[s] = S0c + (size_t)s * rows * HD;
            ga.B[s] = W0t + (size_t)s * 65536;
            ga.a_f32[s] = 0;
        }
        ga.A[5] = x + (size_t)c0 * HD; ga.a_f32[5] = 1; ga.B[5] = Wl0t;
        ga.nseg = 6; ga.bias = b0;
        ga.Cb = h0b + (size_t)c0 * HD; ga.Cf = nullptr;
        ga.M = rows; ga.N = HD;
        gemm_mfma_kernel<<<dim3(2, (rows + 127) / 128), 256, 0, stream>>>(ga);
    }
    bn_stats_kernel<<<256, 256, 0, stream>>>(h0b, ND0, st);
    bn_apply_kernel<<<(ND0 * 64) / 256, 256, 0, stream>>>(h0b, ND0, st, g0, be0, 0);

    // ---------------- layer 1 ----------------------------------------------
    hipMemsetAsync(cnt, 0, NREL * ND1 * sizeof(int), stream);
    count_kernel<<<(E1 + 255) / 256, 256, 0, stream>>>(dst1, et1, E1, ND1, cnt, pos);
    scan_block_kernel<<<(NREL * ND1 + 1023) / 1024, 256, 0, stream>>>(cnt, off, bsum, NREL * ND1);
    scan_block_kernel<<<1, 256, 0, stream>>>(bsum, bsum, nullptr, (NREL * ND1 + 1023) / 1024);
    scan_add_kernel<<<(NREL * ND1 + 255) / 256, 256, 0, stream>>>(off, bsum, NREL * ND1);
    fill_kernel<<<(E1 + 255) / 256, 256, 0, stream>>>(src1, dst1, et1, pos, off, E1, ND1, ssrc);

    gather_b16_kernel<<<(NREL * ND1 * 64) / 256, 256, 0, stream>>>(
        h0b, ssrc, cnt, off, ND1, 0, ND1, S1);
    {
        GemmArgs ga = {};
        for (int s = 0; s < NREL; s++) {
            ga.A[s] = S1 + (size_t)s * ND1 * HD;
            ga.B[s] = W1t + (size_t)s * 65536;
            ga.a_f32[s] = 0;
        }
        ga.A[5] = h0b; ga.a_f32[5] = 0; ga.B[5] = Wl1t;
        ga.nseg = 6; ga.bias = b1;
        ga.Cb = h1b; ga.Cf = nullptr; ga.M = ND1; ga.N = HD;
        gemm_mfma_kernel<<<dim3(2, (ND1 + 127) / 128), 256, 0, stream>>>(ga);
    }
    bn_stats_kernel<<<256, 256, 0, stream>>>(h1b, ND1, st + 512);
    bn_apply_kernel<<<(ND1 * 64) / 256, 256, 0, stream>>>(h1b, ND1, st + 512, g1, be1, 0);

    // ---------------- MLP head ---------------------------------------------
    {
        GemmArgs ga = {};
        ga.A[0] = h1b; ga.a_f32[0] = 0; ga.B[0] = Wm1t;
        ga.nseg = 1; ga.bias = bm1;
        ga.Cb = mb; ga.Cf = nullptr; ga.M = ND1; ga.N = HD;
        gemm_mfma_kernel<<<dim3(2, (ND1 + 127) / 128), 256, 0, stream>>>(ga);
    }
    bn_stats_kernel<<<256, 256, 0, stream>>>(mb, ND1, st + 1024);
    bn_apply_kernel<<<(ND1 * 64) / 256, 256, 0, stream>>>(mb, ND1, st + 1024, gm, bem, 1);
    {
        GemmArgs ga = {};
        ga.A[0] = mb; ga.a_f32[0] = 0; ga.B[0] = Wm2t;
        ga.nseg = 1; ga.bias = bm2;
        ga.Cb = nullptr; ga.Cf = (float*)d_out; ga.M = ND1; ga.N = NOUT;
        gemm_mfma_kernel<<<dim3(2, (ND1 + 127) / 128), 256, 0, stream>>>(ga);
    }
}